// Round 14
// baseline (256.951 us; speedup 1.0000x reference)
//
#include <hip/hip_runtime.h>
#include <hip/hip_bf16.h>

// B=4, S=2048, D=512. fp32 in/out, bf16 MFMA internals.
// Key identity: multiplicative causal mask => E = 1 + F, F = expm1(scale*s) on
// the lower triangle (q>=k), 0 above. Then
//   out  = F @ vp'  +  T,   T[b,d] = sum_k vp'[b,k,d]
//   Z[k] = 2048 + colsum(F)
//
// R13: persistent-kernel v2. R12 accounting: ~110us kernels (GEMM rate pinned
//      on the m102 shape curve across 11 structural variants) + ~50us of
//      launch boundaries (5 dispatches). R3's fusion failed on its BARRIER
//      (single counter: 768 serialized RMWs + 768 pollers on one line), not
//      on the phases. v2: ONE kernel, 512 blocks (exact 2/CU capacity) with a
//      two-level tree barrier: 8 partition counters (64 arrivals each,
//      separate 256B lines) -> 1 root (8 RMWs) -> 8 release flags, local
//      polling with s_sleep. Phase bodies byte-identical to R12 (outF
//      converted to 48KB double-buffer to fit the shared 64KB LDS; that knob
//      was proven flat). vb/Wvb in d_out scratch (R10 race fix). Bounded
//      spin -> FAIL not hang if co-residency breaks.

#define S_LEN 2048
#define D_DIM 512
#define SCALE_F 0.044194173824159216f  // 1/sqrt(512)

typedef __attribute__((ext_vector_type(8))) short s8v;   // 8 bf16 = 4 VGPRs
typedef __attribute__((ext_vector_type(4))) short s4v;   // 4 bf16 = 8 B
typedef __attribute__((ext_vector_type(4))) float f4v;   // MFMA accumulator

enum { EPI_BIAS = 0, EPI_BIAS_T = 1, EPI_SCORES = 2 };

#define SBAR()    __builtin_amdgcn_s_barrier()
#define SCHEDB()  __builtin_amdgcn_sched_barrier(0)
#define WAITV(n)  asm volatile("s_waitcnt vmcnt(" #n ")")
#define WAITL0()  asm volatile("s_waitcnt lgkmcnt(0)")

__device__ __forceinline__ short f2bf_s(float f) {
  union { __hip_bfloat16 b; short s; } u; u.b = __float2bfloat16(f); return u.s;
}
__device__ __forceinline__ float bf2f_s(short h) {
  union { short s; __hip_bfloat16 b; } u; u.s = h; return __bfloat162float(u.b);
}

__device__ __forceinline__ void glds16(const short* g, short* l) {
  __builtin_amdgcn_global_load_lds((const __attribute__((address_space(1))) void*)g,
                                   (__attribute__((address_space(3))) void*)l, 16, 0, 0);
}

// LDS byte offset of a __shared__-derived pointer (addrspace(3) is 32-bit).
__device__ __forceinline__ unsigned lds_addr(const short* p) {
  return (unsigned)(unsigned long long)(const __attribute__((address_space(3))) short*)p;
}

// Inline-asm ds_read_b128: keeps the counted WAITV authoritative. MUST be
// followed by lgkmcnt(0)+SCHEDB before any consumer (rule 18).
__device__ __forceinline__ s8v dsr128(unsigned a) {
  s8v r;
  asm volatile("ds_read_b128 %0, %1" : "=&v"(r) : "v"(a));
  return r;
}

// Two-level grid barrier for 512 co-resident blocks. bars layout (ints):
//   [g*64]      arrival counter for partition g = bid&7 (256B apart)
//   [g*64 + 32] release flag for partition g (own 128B line)
//   [512]       root counter
// Monotone counters; phase p complete when rel > p. Bounded spin.
__device__ __forceinline__ void gsync(int* bars, int phase) {
  __syncthreads();
  if (threadIdx.x == 0) {
    const int g = (int)(blockIdx.x & 7);
    int* cnt = bars + g * 64;
    int* rel = bars + g * 64 + 32;
    __threadfence();   // release: all prior global writes visible
    const int a = __hip_atomic_fetch_add(cnt, 1, __ATOMIC_RELAXED, __HIP_MEMORY_SCOPE_AGENT);
    if (a == phase * 64 + 63) {            // last arrival in this partition
      int* root = bars + 512;
      const int r = __hip_atomic_fetch_add(root, 1, __ATOMIC_RELAXED, __HIP_MEMORY_SCOPE_AGENT);
      if (r == phase * 8 + 7) {            // last partition -> release all
#pragma unroll
        for (int x = 0; x < 8; ++x)
          __hip_atomic_store(bars + x * 64 + 32, phase + 1,
                             __ATOMIC_RELAXED, __HIP_MEMORY_SCOPE_AGENT);
      }
    }
    int guard = 0;
    while (__hip_atomic_load(rel, __ATOMIC_RELAXED, __HIP_MEMORY_SCOPE_AGENT) <= phase) {
      __builtin_amdgcn_s_sleep(2);
      if (++guard > (1 << 20)) break;      // broken barrier -> FAIL, not hang
    }
    __threadfence();   // acquire
  }
  __syncthreads();
}

// ---------------------------------------------------------------------------
// Core NT GEMM, 128x128 tile at (m0,n0), BK=64, LDS double buffer (64 KB).
// Per iter: stage i+1 -> counted WAITV(8) (tile i landed, i+1 in flight) ->
// SBAR -> 2 phases {asm ds_read, lgkmcnt(0), setprio(1), 16 MFMA} -> SBAR.
template <int EPI>
__device__ __forceinline__ void gemm_core(
    const short* __restrict__ A, const short* __restrict__ B,
    short* __restrict__ C, const float* __restrict__ bias,
    short* SMEM, int N, int K, size_t sCz, int m0, int n0, int bz,
    float* __restrict__ Z)
{
  const int tid  = threadIdx.x;
  const int w    = tid >> 6;
  const int lane = tid & 63;
  const int quad = lane >> 4;
  const int l16  = lane & 15;
  const int wm   = (w >> 1) * 64;
  const int wn   = (w & 1) * 64;

  const int strow = tid >> 3;                         // 0..31
  const int gl = ((tid & 7) ^ (strow & 7)) * 8;       // XOR column-octet swizzle

  f4v acc[4][4];
#pragma unroll
  for (int i = 0; i < 4; ++i)
#pragma unroll
    for (int j = 0; j < 4; ++j)
#pragma unroll
      for (int r = 0; r < 4; ++r) acc[i][j][r] = 0.0f;

  const short* Ag = A + (size_t)(m0 + strow) * K + gl;
  const short* Bg = B + (size_t)(n0 + strow) * K + gl;
  const size_t pstr = (size_t)32 * K;
  const int t8 = tid * 8;
  const int swq = l16 & 7;

  const unsigned base = lds_addr(SMEM);
  unsigned aoff[4], boff[4];
#pragma unroll
  for (int ii = 0; ii < 4; ++ii)
    aoff[ii] = base + (unsigned)((wm + ii * 16 + l16) * 128 + ((quad ^ swq) * 16));
#pragma unroll
  for (int j = 0; j < 4; ++j)
    boff[j] = base + 16384u + (unsigned)((wn + j * 16 + l16) * 128 + ((quad ^ swq) * 16));

  const int niter = K >> 6;

#pragma unroll
  for (int p = 0; p < 4; ++p) glds16(Ag + p * pstr, SMEM + t8 + p * 2048);
#pragma unroll
  for (int p = 0; p < 4; ++p) glds16(Bg + p * pstr, SMEM + 8192 + t8 + p * 2048);

  for (int i = 0; i < niter; ++i) {
    const int c = i & 1;
    if (i + 1 < niter) {
      const int k1 = (i + 1) << 6;
      short* dA = SMEM + (1 - c) * 16384 + t8;
#pragma unroll
      for (int p = 0; p < 4; ++p) glds16(Ag + k1 + p * pstr, dA + p * 2048);
#pragma unroll
      for (int p = 0; p < 4; ++p) glds16(Bg + k1 + p * pstr, dA + 8192 + p * 2048);
      SCHEDB();
      WAITV(8);          // tile i landed; tile i+1's 8 stay in flight
    } else {
      WAITV(0);
    }
    SBAR();
    SCHEDB();

    const unsigned cofs = (unsigned)(c << 15);
#pragma unroll
    for (int kk = 0; kk < 2; ++kk) {
      const unsigned kx = (unsigned)(kk << 6);
      s8v af[4], bf[4];
#pragma unroll
      for (int ii = 0; ii < 4; ++ii) af[ii] = dsr128((aoff[ii] ^ kx) + cofs);
#pragma unroll
      for (int j = 0; j < 4; ++j)   bf[j]  = dsr128((boff[j] ^ kx) + cofs);
      WAITL0();
      SCHEDB();
      __builtin_amdgcn_s_setprio(1);
#pragma unroll
      for (int ii = 0; ii < 4; ++ii)
#pragma unroll
        for (int j = 0; j < 4; ++j)
          acc[ii][j] = __builtin_amdgcn_mfma_f32_16x16x32_bf16(af[ii], bf[j], acc[ii][j], 0, 0, 0);
      __builtin_amdgcn_s_setprio(0);
    }
    SBAR();              // buf c free for next iter's prefetch
  }

  // ---- epilogue ----
  float bv[4];
  if (EPI == EPI_BIAS || EPI == EPI_BIAS_T) {
#pragma unroll
    for (int j = 0; j < 4; ++j) bv[j] = bias[n0 + wn + j * 16 + l16];
  }

  if (EPI == EPI_BIAS_T) {
#pragma unroll
    for (int i = 0; i < 4; ++i) {
#pragma unroll
      for (int j = 0; j < 4; ++j) {
        const int gn  = n0 + wn + j * 16 + l16;
        const int gmb = m0 + wm + i * 16 + quad * 4;
        const int bb = gmb >> 11, ssb = gmb & (S_LEN - 1);
        s4v o;
#pragma unroll
        for (int r = 0; r < 4; ++r) o[r] = f2bf_s(acc[i][j][r] + bv[j]);
        *(s4v*)&C[((size_t)bb * D_DIM + gn) * S_LEN + ssb] = o;
      }
    }
    return;
  }

  // EPI_BIAS / EPI_SCORES: LDS transpose -> coalesced 16B row stores.
  short* TB = SMEM;                 // 4 waves x 2176 shorts (32 rows x stride 68)
  const int wbase = w * 2176;
  float csum[4] = {0.f, 0.f, 0.f, 0.f};

#pragma unroll
  for (int ph = 0; ph < 2; ++ph) {
    __syncthreads();
#pragma unroll
    for (int ii = 0; ii < 2; ++ii) {
      const int i = ph * 2 + ii;
#pragma unroll
      for (int j = 0; j < 4; ++j) {
        const int gn = n0 + wn + j * 16 + l16;
#pragma unroll
        for (int r = 0; r < 4; ++r) {
          short o;
          if (EPI == EPI_SCORES) {
            const int gm = m0 + wm + i * 16 + quad * 4 + r;
            const float f = (gm >= gn) ? (__expf(acc[i][j][r] * SCALE_F) - 1.0f) : 0.0f;
            csum[j] += f;
            o = f2bf_s(f);
          } else {
            o = f2bf_s(acc[i][j][r] + bv[j]);
          }
          TB[wbase + (ii * 16 + quad * 4 + r) * 68 + j * 16 + l16] = o;
        }
      }
    }
    __syncthreads();
#pragma unroll
    for (int p = 0; p < 4; ++p) {
      const int row = p * 8 + (lane >> 3);   // 0..31
      const int cg  = lane & 7;
      const s8v vv = *(const s8v*)&TB[wbase + row * 68 + cg * 8];
      const int gm = m0 + wm + ph * 32 + row;
      const int gn = n0 + wn + cg * 8;
      *(s8v*)&C[sCz + (size_t)gm * N + gn] = vv;
    }
  }

  if (EPI == EPI_SCORES) {
#pragma unroll
    for (int j = 0; j < 4; ++j) {
      float cs = csum[j];
      cs += __shfl_xor(cs, 16, 64);
      cs += __shfl_xor(cs, 32, 64);
      if (quad == 0) atomicAdd(&Z[(bz << 11) + n0 + wn + j * 16 + l16], cs);
    }
  }
}

// outF body, 64x128 tile, BK=64, DOUBLE-buffered (48 KB of SMEM), K-trunc.
__device__ __forceinline__ void outF_body(
    const short* __restrict__ F, const short* __restrict__ vpT,
    const float* __restrict__ Tv, float* __restrict__ out,
    int bz, int mi, int n0, short* SMEM)
{
  const int tid  = threadIdx.x;
  const int m0   = mi * 64;

  const short* A = F   + (size_t)bz * S_LEN * S_LEN;
  const short* B = vpT + (size_t)bz * D_DIM * S_LEN;

  const int w    = tid >> 6;
  const int lane = tid & 63;
  const int quad = lane >> 4;
  const int l16  = lane & 15;
  const int wm   = (w >> 1) * 32;
  const int wn   = (w & 1) * 64;

  const int strow = tid >> 3;
  const int gl = ((tid & 7) ^ (strow & 7)) * 8;

  f4v acc[2][4];
#pragma unroll
  for (int i = 0; i < 2; ++i)
#pragma unroll
    for (int j = 0; j < 4; ++j)
#pragma unroll
      for (int r = 0; r < 4; ++r) acc[i][j][r] = 0.0f;

  const short* Ag = A + (size_t)(m0 + strow) * S_LEN + gl;
  const short* Bg = B + (size_t)(n0 + strow) * S_LEN + gl;
  const size_t pstr = (size_t)32 * S_LEN;
  const int t8 = tid * 8;
  const int swq = l16 & 7;

  const unsigned base = lds_addr(SMEM);
  unsigned aoff[2], boff[4];
#pragma unroll
  for (int ii = 0; ii < 2; ++ii)
    aoff[ii] = base + (unsigned)((wm + ii * 16 + l16) * 128 + ((quad ^ swq) * 16));
#pragma unroll
  for (int j = 0; j < 4; ++j)
    boff[j] = base + 8192u + (unsigned)((wn + j * 16 + l16) * 128 + ((quad ^ swq) * 16));

  const int niter = mi + 1;   // K runs 0 .. m0+64

  // preload tile 0 into buf 0 (6 loads: A x2, B x4)
#pragma unroll
  for (int p = 0; p < 2; ++p) glds16(Ag + p * pstr, SMEM + t8 + p * 2048);
#pragma unroll
  for (int p = 0; p < 4; ++p) glds16(Bg + p * pstr, SMEM + 4096 + t8 + p * 2048);

  for (int i = 0; i < niter; ++i) {
    const int c = i & 1;
    if (i + 1 < niter) {
      const int k1 = (i + 1) << 6;
      short* dst = SMEM + (1 - c) * 12288 + t8;
#pragma unroll
      for (int p = 0; p < 2; ++p) glds16(Ag + k1 + p * pstr, dst + p * 2048);
#pragma unroll
      for (int p = 0; p < 4; ++p) glds16(Bg + k1 + p * pstr, dst + 4096 + p * 2048);
      SCHEDB();
      WAITV(6);          // tile i landed; tile i+1's 6 stay in flight
    } else {
      WAITV(0);
    }
    SBAR();
    SCHEDB();

    const unsigned cofs = (unsigned)(c * 24576);
#pragma unroll
    for (int kk = 0; kk < 2; ++kk) {
      const unsigned kx = (unsigned)(kk << 6);
      s8v af[2], bf[4];
#pragma unroll
      for (int ii = 0; ii < 2; ++ii) af[ii] = dsr128((aoff[ii] ^ kx) + cofs);
#pragma unroll
      for (int j = 0; j < 4; ++j)   bf[j]  = dsr128((boff[j] ^ kx) + cofs);
      WAITL0();
      SCHEDB();
      __builtin_amdgcn_s_setprio(1);
#pragma unroll
      for (int ii = 0; ii < 2; ++ii)
#pragma unroll
        for (int j = 0; j < 4; ++j)
          acc[ii][j] = __builtin_amdgcn_mfma_f32_16x16x32_bf16(af[ii], bf[j], acc[ii][j], 0, 0, 0);
      __builtin_amdgcn_s_setprio(0);
    }
    SBAR();              // buf c free for next iter's prefetch
  }

  float* Cf = out + (size_t)bz * S_LEN * D_DIM;
#pragma unroll
  for (int i = 0; i < 2; ++i) {
#pragma unroll
    for (int j = 0; j < 4; ++j) {
      const int gn = n0 + wn + j * 16 + l16;
      const float tvn = Tv[(bz << 9) + gn];
#pragma unroll
      for (int r = 0; r < 4; ++r) {
        const int gm = m0 + wm + i * 16 + quad * 4 + r;
        Cf[(size_t)gm * D_DIM + gn] = acc[i][j][r] + tvn;
      }
    }
  }
}

// ---------------- the persistent pipeline ----------------
__global__ __launch_bounds__(256, 2) void fused_pipeline(
    const float* __restrict__ q, const float* __restrict__ k, const float* __restrict__ v,
    const float* __restrict__ WQw, const float* __restrict__ WQb,
    const float* __restrict__ WKw, const float* __restrict__ WKb,
    const float* __restrict__ WVw, const float* __restrict__ WVb,
    char* __restrict__ ws, float* __restrict__ out, int* __restrict__ bars)
{
  __shared__ __align__(16) short SMEM[32768];   // 64 KB
  const int bid = blockIdx.x;
  const int tid = threadIdx.x;
  const int tg  = bid * 256 + tid;              // 0..131071

  // workspace (F aliases qb/kb/Wqb/Wkb, all dead before any F write);
  // vb/Wvb in d_out scratch (read while F is written; out fully rewritten
  // by phase 4).
  short* F   = (short*)(ws);                 // 32 MB lower tiles
  short* qb  = (short*)(ws);                 //  8 MB
  short* kb  = qb + 4194304;                 //  8 MB
  short* Wqb = (short*)(ws + 25165824);      //  512 KB
  short* Wkb = Wqb + 262144;
  short* qp  = (short*)(ws + 33554432);      //  8 MB
  short* kp  = (short*)(ws + 41943040);      //  8 MB
  short* vpT = (short*)(ws + 50331648);      //  8 MB  [4][512][2048]
  float* ZF  = (float*)(ws + 58720256);      // 32 KB  [4][2048]
  float* Tv  = (float*)(ws + 58753024);      //  8 KB  [4][512]
  short* vb  = (short*)out;                  //  8 MB  (out scratch)
  short* Wvb = (short*)out + 4194304;        //  512 KB

  // ---- phase 0: fp32 -> bf16 conversions + ZF zero ----
  {
#pragma unroll 2
    for (int sw = 0; sw < 12; ++sw) {
      const int e = (sw * 131072 + tg) * 8;            // < 12582912
      const float* s; short* d; int off;
      if (e < 4194304)       { s = q; d = qb; off = e; }
      else if (e < 8388608)  { s = k; d = kb; off = e - 4194304; }
      else                   { s = v; d = vb; off = e - 8388608; }
      const float4 f0 = *(const float4*)(s + off);
      const float4 f1 = *(const float4*)(s + off + 4);
      s8v o;
      o[0] = f2bf_s(f0.x); o[1] = f2bf_s(f0.y); o[2] = f2bf_s(f0.z); o[3] = f2bf_s(f0.w);
      o[4] = f2bf_s(f1.x); o[5] = f2bf_s(f1.y); o[6] = f2bf_s(f1.z); o[7] = f2bf_s(f1.w);
      *(s8v*)(d + off) = o;
    }
    if (tg < 98304) {
      const int e = tg * 8;                            // < 786432
      const float* s; short* d; int off;
      if (e < 262144)        { s = WQw; d = Wqb; off = e; }
      else if (e < 524288)   { s = WKw; d = Wkb; off = e - 262144; }
      else                   { s = WVw; d = Wvb; off = e - 524288; }
      const float4 f0 = *(const float4*)(s + off);
      const float4 f1 = *(const float4*)(s + off + 4);
      s8v o;
      o[0] = f2bf_s(f0.x); o[1] = f2bf_s(f0.y); o[2] = f2bf_s(f0.z); o[3] = f2bf_s(f0.w);
      o[4] = f2bf_s(f1.x); o[5] = f2bf_s(f1.y); o[6] = f2bf_s(f1.z); o[7] = f2bf_s(f1.w);
      *(s8v*)(d + off) = o;
    }
    if (tg < 8192) ZF[tg] = 0.0f;
  }
  gsync(bars, 0);

  // ---- phase 1: q,k projections (512 tiles, 1 per block) ----
  {
    const int bsw = (bid & 7) * 64 + (bid >> 3);  // bijective over 512
    const int z   = bsw >> 8;                     // 0 or 1
    const int rem = bsw & 255;
    const int m0  = (rem >> 2) * 128;
    const int n0  = (rem & 3) * 128;
    const short* A = z ? kb : qb;
    const short* B = z ? Wkb : Wqb;
    short*       C = z ? kp : qp;
    const float* bias = z ? WKb : WQb;
    gemm_core<EPI_BIAS>(A, B, C, bias, SMEM, D_DIM, D_DIM, 0, m0, n0, 0, nullptr);
  }
  gsync(bars, 1);

  // ---- phase 2: scores (544) + vpT projection (256); tiles bid, bid+512 ----
  for (int rep = 0; rep < 2; ++rep) {
    const int t = bid + rep * 512;
    if (t >= 800) break;
    if (t < 544) {
      const int bsw = (t & 7) * 68 + (t >> 3);    // bijective over 544
      const int bz  = bsw / 136;
      const int tt  = bsw - bz * 136;
      int ti = (int)((sqrtf(8.0f * tt + 1.0f) - 1.0f) * 0.5f);
      while ((ti + 1) * (ti + 2) / 2 <= tt) ++ti;
      while (ti * (ti + 1) / 2 > tt) --ti;
      const int tj = tt - ti * (ti + 1) / 2;      // tj <= ti
      gemm_core<EPI_SCORES>(qp + (size_t)bz * S_LEN * D_DIM, kp + (size_t)bz * S_LEN * D_DIM,
                            F, nullptr, SMEM, S_LEN, D_DIM,
                            (size_t)bz * S_LEN * S_LEN, ti * 128, tj * 128, bz, ZF);
    } else {
      const int h   = t - 544;                    // 0..255
      const int hsw = (h & 7) * 32 + (h >> 3);    // bijective over 256
      const int m0  = (hsw >> 2) * 128;
      const int n0  = (hsw & 3) * 128;
      gemm_core<EPI_BIAS_T>(vb, Wvb, vpT, WVb, SMEM, D_DIM, D_DIM, 0, m0, n0, 0, nullptr);
    }
  }
  gsync(bars, 2);

  // ---- phase 3: vpT /= (2048+ZF); Tv = rowsum (4 rows per block) ----
  {
    float* red = (float*)SMEM;
#pragma unroll
    for (int it = 0; it < 4; ++it) {
      const int r = bid + 512 * it;               // < 2048
      const int b = r >> 9, d = r & 511;
      const size_t rowbase = ((size_t)(b * D_DIM + d)) * S_LEN;
      const float* zf = ZF + (b << 11);
      const int k0 = tid * 8;
      s8v vv = *(s8v*)&vpT[rowbase + k0];
      float s = 0.0f;
#pragma unroll
      for (int i = 0; i < 8; ++i) {
        const float wgt = bf2f_s(vv[i]) / (2048.0f + zf[k0 + i]);
        s += wgt;
        vv[i] = f2bf_s(wgt);
      }
      *(s8v*)&vpT[rowbase + k0] = vv;
#pragma unroll
      for (int off = 32; off >= 1; off >>= 1) s += __shfl_xor(s, off, 64);
      if ((tid & 63) == 0) red[tid >> 6] = s;
      __syncthreads();
      if (tid == 0) Tv[(b << 9) + d] = red[0] + red[1] + red[2] + red[3];
      __syncthreads();
    }
  }
  gsync(bars, 3);

  // ---- phase 4: out = F @ vpT'^T + Tv (R12's XCD-local mapping) ----
  {
    const int x     = bid & 7;
    const int s     = bid >> 3;
    const int n0    = (s & 3) * 128;
    const int bz    = (s >> 2) & 3;
    const int zslot = s >> 4;                     // 0..3
    const int zs    = (zslot < 2) ? (2 * x + zslot) : (16 + 2 * x + (zslot - 2));
    const int mi    = (zs < 16) ? (31 - zs) : (zs - 16);
    outF_body(F, vpT, Tv, out, bz, mi, n0, SMEM);
  }
}

extern "C" void kernel_launch(void* const* d_in, const int* in_sizes, int n_in,
                              void* d_out, int out_size, void* d_ws, size_t ws_size,
                              hipStream_t stream) {
  const float* q   = (const float*)d_in[0];
  const float* k   = (const float*)d_in[1];
  const float* v   = (const float*)d_in[2];
  const float* WQw = (const float*)d_in[3];
  const float* WQb = (const float*)d_in[4];
  const float* WKw = (const float*)d_in[5];
  const float* WKb = (const float*)d_in[6];
  const float* WVw = (const float*)d_in[7];
  const float* WVb = (const float*)d_in[8];

  char* ws = (char*)d_ws;
  int* bars = (int*)(ws + 58761216);   // 4 KB barrier region (after Tv)

  (void)hipMemsetAsync(bars, 0, 4096, stream);

  fused_pipeline<<<dim3(512), dim3(256), 0, stream>>>(
      q, k, v, WQw, WQb, WKw, WKb, WVw, WVb,
      ws, (float*)d_out, bars);
}

// Round 15
// 185.383 us; speedup vs baseline: 1.3861x; 1.3861x over previous
//
#include <hip/hip_runtime.h>
#include <hip/hip_bf16.h>

// B=4, S=2048, D=512. fp32 in/out, bf16 MFMA internals.
// Key identity: multiplicative causal mask => E = 1 + F, F = expm1(scale*s) on
// the lower triangle (q>=k), 0 above. Then
//   out  = F @ vp'  +  T,   T[b,d] = sum_k vp'[b,k,d]
//   Z[k] = 2048 + colsum(F)
// Pipeline: cvt_all(+ZF0,Tv0) | proj_qk | scores_projv(+scale fused) | outF
//
// R14: revert R13 (persistent fusion dead twice: in-kernel device barriers
//      cost >= launch boundaries). Base = R12 (best, 162.4us). New: the
//      scale_vpt_T dispatch is folded into scores_projv via a PARTIAL-ORDER
//      producer counter (not a grid barrier): scores blocks increment `done`
//      after their ZF adds drain; vpT-projection blocks spin on done==544
//      AFTER their GEMM, then scale in-register in the epilogue
//      (scaled=(acc+bias)/(2048+ZF[k])), write scaled vpT, and atomicAdd
//      per-d partial sums into Tv. Unconditionally deadlock-free: capacity
//      512, only 256 vpT blocks -> >=256 slots always available for scores.
//      Bounded spin -> FAIL not hang. Removes 16MB scale traffic + 1 launch
//      boundary. All else byte-identical to R12.

#define S_LEN 2048
#define D_DIM 512
#define SCALE_F 0.044194173824159216f  // 1/sqrt(512)

typedef __attribute__((ext_vector_type(8))) short s8v;   // 8 bf16 = 4 VGPRs
typedef __attribute__((ext_vector_type(4))) short s4v;   // 4 bf16 = 8 B
typedef __attribute__((ext_vector_type(4))) float f4v;   // MFMA accumulator

enum { EPI_BIAS = 0, EPI_BIAS_T = 1, EPI_SCORES = 2, EPI_BIAS_T_SCALED = 3 };

#define SBAR()    __builtin_amdgcn_s_barrier()
#define SCHEDB()  __builtin_amdgcn_sched_barrier(0)
#define WAITV(n)  asm volatile("s_waitcnt vmcnt(" #n ")")
#define WAITL0()  asm volatile("s_waitcnt lgkmcnt(0)")

__device__ __forceinline__ short f2bf_s(float f) {
  union { __hip_bfloat16 b; short s; } u; u.b = __float2bfloat16(f); return u.s;
}
__device__ __forceinline__ float bf2f_s(short h) {
  union { short s; __hip_bfloat16 b; } u; u.s = h; return __bfloat162float(u.b);
}

__device__ __forceinline__ void glds16(const short* g, short* l) {
  __builtin_amdgcn_global_load_lds((const __attribute__((address_space(1))) void*)g,
                                   (__attribute__((address_space(3))) void*)l, 16, 0, 0);
}

// LDS byte offset of a __shared__-derived pointer (addrspace(3) is 32-bit).
__device__ __forceinline__ unsigned lds_addr(const short* p) {
  return (unsigned)(unsigned long long)(const __attribute__((address_space(3))) short*)p;
}

// Inline-asm ds_read_b128: keeps the counted WAITV authoritative. MUST be
// followed by lgkmcnt(0)+SCHEDB before any consumer (rule 18).
__device__ __forceinline__ s8v dsr128(unsigned a) {
  s8v r;
  asm volatile("ds_read_b128 %0, %1" : "=&v"(r) : "v"(a));
  return r;
}

// ---------------------------------------------------------------------------
// Core NT GEMM, 128x128 tile at (m0,n0), BK=64, LDS double buffer (64 KB).
// Per iter: stage i+1 -> counted WAITV(8) (tile i landed, i+1 in flight) ->
// SBAR -> 2 phases {asm ds_read, lgkmcnt(0), setprio(1), 16 MFMA} -> SBAR.
// EPI_BIAS_T_SCALED: after GEMM, spin on done==544 (all scores ZF adds in),
// then scaled transposed write + Tv partial-sum atomics.
template <int EPI>
__device__ __forceinline__ void gemm_core(
    const short* __restrict__ A, const short* __restrict__ B,
    short* __restrict__ C, const float* __restrict__ bias,
    short* SMEM, int N, int K, size_t sCz, int m0, int n0, int bz,
    float* __restrict__ Z, float* __restrict__ TvP, int* __restrict__ done)
{
  const int tid  = threadIdx.x;
  const int w    = tid >> 6;
  const int lane = tid & 63;
  const int quad = lane >> 4;
  const int l16  = lane & 15;
  const int wm   = (w >> 1) * 64;
  const int wn   = (w & 1) * 64;

  const int strow = tid >> 3;                         // 0..31
  const int gl = ((tid & 7) ^ (strow & 7)) * 8;       // XOR column-octet swizzle

  f4v acc[4][4];
#pragma unroll
  for (int i = 0; i < 4; ++i)
#pragma unroll
    for (int j = 0; j < 4; ++j)
#pragma unroll
      for (int r = 0; r < 4; ++r) acc[i][j][r] = 0.0f;

  const short* Ag = A + (size_t)(m0 + strow) * K + gl;
  const short* Bg = B + (size_t)(n0 + strow) * K + gl;
  const size_t pstr = (size_t)32 * K;
  const int t8 = tid * 8;
  const int swq = l16 & 7;

  const unsigned base = lds_addr(SMEM);
  unsigned aoff[4], boff[4];
#pragma unroll
  for (int ii = 0; ii < 4; ++ii)
    aoff[ii] = base + (unsigned)((wm + ii * 16 + l16) * 128 + ((quad ^ swq) * 16));
#pragma unroll
  for (int j = 0; j < 4; ++j)
    boff[j] = base + 16384u + (unsigned)((wn + j * 16 + l16) * 128 + ((quad ^ swq) * 16));

  const int niter = K >> 6;

#pragma unroll
  for (int p = 0; p < 4; ++p) glds16(Ag + p * pstr, SMEM + t8 + p * 2048);
#pragma unroll
  for (int p = 0; p < 4; ++p) glds16(Bg + p * pstr, SMEM + 8192 + t8 + p * 2048);

  for (int i = 0; i < niter; ++i) {
    const int c = i & 1;
    if (i + 1 < niter) {
      const int k1 = (i + 1) << 6;
      short* dA = SMEM + (1 - c) * 16384 + t8;
#pragma unroll
      for (int p = 0; p < 4; ++p) glds16(Ag + k1 + p * pstr, dA + p * 2048);
#pragma unroll
      for (int p = 0; p < 4; ++p) glds16(Bg + k1 + p * pstr, dA + 8192 + p * 2048);
      SCHEDB();
      WAITV(8);          // tile i landed; tile i+1's 8 stay in flight
    } else {
      WAITV(0);
    }
    SBAR();
    SCHEDB();

    const unsigned cofs = (unsigned)(c << 15);
#pragma unroll
    for (int kk = 0; kk < 2; ++kk) {
      const unsigned kx = (unsigned)(kk << 6);
      s8v af[4], bf[4];
#pragma unroll
      for (int ii = 0; ii < 4; ++ii) af[ii] = dsr128((aoff[ii] ^ kx) + cofs);
#pragma unroll
      for (int j = 0; j < 4; ++j)   bf[j]  = dsr128((boff[j] ^ kx) + cofs);
      WAITL0();
      SCHEDB();
      __builtin_amdgcn_s_setprio(1);
#pragma unroll
      for (int ii = 0; ii < 4; ++ii)
#pragma unroll
        for (int j = 0; j < 4; ++j)
          acc[ii][j] = __builtin_amdgcn_mfma_f32_16x16x32_bf16(af[ii], bf[j], acc[ii][j], 0, 0, 0);
      __builtin_amdgcn_s_setprio(0);
    }
    SBAR();              // buf c free for next iter's prefetch
  }

  // ---- epilogue ----
  float bv[4];
  if (EPI == EPI_BIAS || EPI == EPI_BIAS_T || EPI == EPI_BIAS_T_SCALED) {
#pragma unroll
    for (int j = 0; j < 4; ++j) bv[j] = bias[n0 + wn + j * 16 + l16];
  }

  if (EPI == EPI_BIAS_T) {
#pragma unroll
    for (int i = 0; i < 4; ++i) {
#pragma unroll
      for (int j = 0; j < 4; ++j) {
        const int gn  = n0 + wn + j * 16 + l16;
        const int gmb = m0 + wm + i * 16 + quad * 4;
        const int bb = gmb >> 11, ssb = gmb & (S_LEN - 1);
        s4v o;
#pragma unroll
        for (int r = 0; r < 4; ++r) o[r] = f2bf_s(acc[i][j][r] + bv[j]);
        *(s4v*)&C[((size_t)bb * D_DIM + gn) * S_LEN + ssb] = o;
      }
    }
    return;
  }

  if (EPI == EPI_BIAS_T_SCALED) {
    // wait for all 544 scores blocks' ZF contributions (partial order, not
    // a barrier; deadlock-free: <=256 of these blocks vs 512 capacity)
    if (tid == 0) {
      int guard = 0;
      while (__hip_atomic_load(done, __ATOMIC_RELAXED, __HIP_MEMORY_SCOPE_AGENT) < 544) {
        __builtin_amdgcn_s_sleep(8);
        if (++guard > (1 << 22)) break;   // broken -> FAIL, not hang
      }
      __threadfence();   // acquire
    }
    __syncthreads();

    const int bb  = m0 >> 11;
    const int kb0 = m0 & (S_LEN - 1);
    const float* zf = Z + (bb << 11);
    float csum[4] = {0.f, 0.f, 0.f, 0.f};
#pragma unroll
    for (int i = 0; i < 4; ++i) {
#pragma unroll
      for (int j = 0; j < 4; ++j) {
        const int gn  = n0 + wn + j * 16 + l16;
        const int kk0 = kb0 + wm + i * 16 + quad * 4;
        s4v o;
#pragma unroll
        for (int r = 0; r < 4; ++r) {
          const float sc = (acc[i][j][r] + bv[j]) / (2048.0f + zf[kk0 + r]);
          csum[j] += sc;
          o[r] = f2bf_s(sc);
        }
        *(s4v*)&C[((size_t)bb * D_DIM + gn) * S_LEN + kk0] = o;
      }
    }
    // Tv partial sums: reduce over quads (k-coverage wm+0..63 per wave),
    // two waves (wm=0,64) + 16 m0-slices per bb complete the 2048-k sum.
#pragma unroll
    for (int j = 0; j < 4; ++j) {
      float cs = csum[j];
      cs += __shfl_xor(cs, 16, 64);
      cs += __shfl_xor(cs, 32, 64);
      if (quad == 0) atomicAdd(&TvP[(bb << 9) + n0 + wn + j * 16 + l16], cs);
    }
    return;
  }

  // EPI_BIAS / EPI_SCORES: LDS transpose -> coalesced 16B row stores.
  short* TB = SMEM;                 // 4 waves x 2176 shorts (32 rows x stride 68)
  const int wbase = w * 2176;
  float csum[4] = {0.f, 0.f, 0.f, 0.f};

#pragma unroll
  for (int ph = 0; ph < 2; ++ph) {
    __syncthreads();
#pragma unroll
    for (int ii = 0; ii < 2; ++ii) {
      const int i = ph * 2 + ii;
#pragma unroll
      for (int j = 0; j < 4; ++j) {
        const int gn = n0 + wn + j * 16 + l16;
#pragma unroll
        for (int r = 0; r < 4; ++r) {
          short o;
          if (EPI == EPI_SCORES) {
            const int gm = m0 + wm + i * 16 + quad * 4 + r;
            const float f = (gm >= gn) ? (__expf(acc[i][j][r] * SCALE_F) - 1.0f) : 0.0f;
            csum[j] += f;
            o = f2bf_s(f);
          } else {
            o = f2bf_s(acc[i][j][r] + bv[j]);
          }
          TB[wbase + (ii * 16 + quad * 4 + r) * 68 + j * 16 + l16] = o;
        }
      }
    }
    __syncthreads();
#pragma unroll
    for (int p = 0; p < 4; ++p) {
      const int row = p * 8 + (lane >> 3);   // 0..31
      const int cg  = lane & 7;
      const s8v vv = *(const s8v*)&TB[wbase + row * 68 + cg * 8];
      const int gm = m0 + wm + ph * 32 + row;
      const int gn = n0 + wn + cg * 8;
      *(s8v*)&C[sCz + (size_t)gm * N + gn] = vv;
    }
  }

  if (EPI == EPI_SCORES) {
#pragma unroll
    for (int j = 0; j < 4; ++j) {
      float cs = csum[j];
      cs += __shfl_xor(cs, 16, 64);
      cs += __shfl_xor(cs, 32, 64);
      if (quad == 0) atomicAdd(&Z[(bz << 11) + n0 + wn + j * 16 + l16], cs);
    }
  }
}

// projections q,k only: 512 full tiles = exactly one dispatch round @2/CU.
__global__ __launch_bounds__(256, 2) void proj_qk(
    const short* __restrict__ a0, const short* __restrict__ a1,
    const short* __restrict__ b0, const short* __restrict__ b1,
    short* __restrict__ c0, short* __restrict__ c1,
    const float* __restrict__ x0, const float* __restrict__ x1)
{
  __shared__ __align__(16) short SMEM[32768];   // 64 KB
  const int bid = blockIdx.x;
  const int bsw = (bid & 7) * 64 + (bid >> 3);  // XCD-bijective (512 = 8x64)
  const int z   = bsw >> 8;                     // 0 or 1
  const int rem = bsw & 255;
  const int m0  = (rem >> 2) * 128;
  const int n0  = (rem & 3) * 128;
  const short* A = z ? a1 : a0;
  const short* B = z ? b1 : b0;
  short*       C = z ? c1 : c0;
  const float* bias = z ? x1 : x0;
  gemm_core<EPI_BIAS>(A, B, C, bias, SMEM, D_DIM, D_DIM, 0, m0, n0, 0,
                      nullptr, nullptr, nullptr);
}

// Fused: 544 scores tiles (need qp/kp; each bumps `done` after its ZF adds
// drain) + 256 vpT projection+SCALE tiles (GEMM from vb/Wvb in d_out scratch,
// then spin on done==544, scale in-register, write scaled vpT + Tv partials).
__global__ __launch_bounds__(256, 2) void scores_projv(
    const short* __restrict__ qp, const short* __restrict__ kp, short* __restrict__ F,
    float* __restrict__ Z,
    const short* __restrict__ vb, const short* __restrict__ Wvb,
    short* __restrict__ vpT, const float* __restrict__ xv,
    float* __restrict__ Tv, int* __restrict__ done)
{
  __shared__ __align__(16) short SMEM[32768];   // 64 KB
  const int bid = blockIdx.x;
  if (bid < 544) {
    const int bsw = (bid & 7) * 68 + (bid >> 3);  // XCD-bijective (544 = 8x68)
    const int bz  = bsw / 136;
    const int t   = bsw - bz * 136;
    int ti = (int)((sqrtf(8.0f * t + 1.0f) - 1.0f) * 0.5f);
    while ((ti + 1) * (ti + 2) / 2 <= t) ++ti;
    while (ti * (ti + 1) / 2 > t) --ti;
    const int tj = t - ti * (ti + 1) / 2;         // tj <= ti
    gemm_core<EPI_SCORES>(qp + (size_t)bz * S_LEN * D_DIM, kp + (size_t)bz * S_LEN * D_DIM,
                          F, nullptr, SMEM, S_LEN, D_DIM,
                          (size_t)bz * S_LEN * S_LEN, ti * 128, tj * 128, bz, Z,
                          nullptr, nullptr);
    // all this block's ZF atomicAdds drained by the syncthreads' vmcnt(0)
    __syncthreads();
    if (threadIdx.x == 0) {
      __threadfence();   // release
      __hip_atomic_fetch_add(done, 1, __ATOMIC_RELAXED, __HIP_MEMORY_SCOPE_AGENT);
    }
  } else {
    const int h   = bid - 544;                    // 0..255
    const int hsw = (h & 7) * 32 + (h >> 3);      // XCD-bijective (256 = 8x32)
    const int m0  = (hsw >> 2) * 128;             // 64 row-tiles of [8192]
    const int n0  = (hsw & 3) * 128;
    gemm_core<EPI_BIAS_T_SCALED>(vb, Wvb, vpT, xv, SMEM, D_DIM, D_DIM, 0, m0, n0, 0,
                                 Z, Tv, done);
  }
}

// out = F @ vpT'^T + T, 64x128 tiles, BK=64, K truncated at m0+64,
// triple-buffered (72 KB), prefetch distance 2 issued AFTER the barrier.
// Grid 512 1-D, XCD-locality mapping (R12): the 4 n-tiles of one F panel and
// the 4 zslots of one vpT panel share an XCD; per-XCD K-work balanced.
__global__ __launch_bounds__(256, 2) void gemm_outF(
    const short* __restrict__ F, const short* __restrict__ vpT,
    const float* __restrict__ Tv, float* __restrict__ out)
{
  __shared__ __align__(16) short SMEM[36864];   // 72 KB

  const int tid  = threadIdx.x;
  const int h    = blockIdx.x;
  const int x    = h & 7;
  const int s    = h >> 3;
  const int n0   = (s & 3) * 128;
  const int bz   = (s >> 2) & 3;
  const int zslot = s >> 4;                     // 0..3
  const int zs   = (zslot < 2) ? (2 * x + zslot) : (16 + 2 * x + (zslot - 2));
  const int mi   = (zs < 16) ? (31 - zs) : (zs - 16);
  const int m0   = mi * 64;

  const short* A = F   + (size_t)bz * S_LEN * S_LEN;
  const short* B = vpT + (size_t)bz * D_DIM * S_LEN;

  const int w    = tid >> 6;
  const int lane = tid & 63;
  const int quad = lane >> 4;
  const int l16  = lane & 15;
  const int wm   = (w >> 1) * 32;
  const int wn   = (w & 1) * 64;

  const int strow = tid >> 3;
  const int gl = ((tid & 7) ^ (strow & 7)) * 8;

  f4v acc[2][4];
#pragma unroll
  for (int i = 0; i < 2; ++i)
#pragma unroll
    for (int j = 0; j < 4; ++j)
#pragma unroll
      for (int r = 0; r < 4; ++r) acc[i][j][r] = 0.0f;

  const short* Ag = A + (size_t)(m0 + strow) * S_LEN + gl;
  const short* Bg = B + (size_t)(n0 + strow) * S_LEN + gl;
  const size_t pstr = (size_t)32 * S_LEN;
  const int t8 = tid * 8;
  const int swq = l16 & 7;

  const unsigned base = lds_addr(SMEM);
  unsigned aoff[2], boff[4];
#pragma unroll
  for (int ii = 0; ii < 2; ++ii)
    aoff[ii] = base + (unsigned)((wm + ii * 16 + l16) * 128 + ((quad ^ swq) * 16));
#pragma unroll
  for (int j = 0; j < 4; ++j)
    boff[j] = base + 8192u + (unsigned)((wn + j * 16 + l16) * 128 + ((quad ^ swq) * 16));

  const int niter = mi + 1;   // K runs 0 .. m0+64

  // preload tiles 0,1 into bufs 0,1 (6 loads each: A x2, B x4)
#pragma unroll
  for (int pre = 0; pre < 2; ++pre) {
    short* dst = SMEM + pre * 12288 + t8;
    const int k0 = pre << 6;
#pragma unroll
    for (int p = 0; p < 2; ++p) glds16(Ag + k0 + p * pstr, dst + p * 2048);
#pragma unroll
    for (int p = 0; p < 4; ++p) glds16(Bg + k0 + p * pstr, dst + 4096 + p * 2048);
  }

  int cbuf = 0;
  for (int i = 0; i < niter; ++i) {
    if (i + 1 < niter) { WAITV(6); } else { WAITV(0); }   // tile i landed
    SBAR();
    SCHEDB();

    if (i + 2 < niter) {          // issue i+2 into the buffer read at i-1
      int nb = cbuf + 2; if (nb >= 3) nb -= 3;
      const int k2 = (i + 2) << 6;
      short* dst = SMEM + nb * 12288 + t8;
#pragma unroll
      for (int p = 0; p < 2; ++p) glds16(Ag + k2 + p * pstr, dst + p * 2048);
#pragma unroll
      for (int p = 0; p < 4; ++p) glds16(Bg + k2 + p * pstr, dst + 4096 + p * 2048);
      SCHEDB();
    }

    const unsigned cofs = (unsigned)(cbuf * 24576);
    cbuf = (cbuf == 2) ? 0 : cbuf + 1;
#pragma unroll
    for (int kk = 0; kk < 2; ++kk) {
      const unsigned kx = (unsigned)(kk << 6);
      s8v af[2], bf[4];
#pragma unroll
      for (int ii = 0; ii < 2; ++ii) af[ii] = dsr128((aoff[ii] ^ kx) + cofs);
#pragma unroll
      for (int j = 0; j < 4; ++j)   bf[j]  = dsr128((boff[j] ^ kx) + cofs);
      WAITL0();
      SCHEDB();
      __builtin_amdgcn_s_setprio(1);
#pragma unroll
      for (int ii = 0; ii < 2; ++ii)
#pragma unroll
        for (int j = 0; j < 4; ++j)
          acc[ii][j] = __builtin_amdgcn_mfma_f32_16x16x32_bf16(af[ii], bf[j], acc[ii][j], 0, 0, 0);
      __builtin_amdgcn_s_setprio(0);
    }
  }

  float* Cf = out + (size_t)bz * S_LEN * D_DIM;
#pragma unroll
  for (int i = 0; i < 2; ++i) {
#pragma unroll
    for (int j = 0; j < 4; ++j) {
      const int gn = n0 + wn + j * 16 + l16;
      const float tvn = Tv[(bz << 9) + gn];
#pragma unroll
      for (int r = 0; r < 4; ++r) {
        const int gm = m0 + wm + i * 16 + quad * 4 + r;
        Cf[(size_t)gm * D_DIM + gn] = acc[i][j][r] + tvn;
      }
    }
  }
}

// fp32 -> bf16, one launch for data (x<2048) and weights (x>=2048);
// zeroes ZF, Tv, and the done counter.
__global__ __launch_bounds__(256) void cvt_all(
    const float* __restrict__ q, const float* __restrict__ k, const float* __restrict__ v,
    const float* __restrict__ wq, const float* __restrict__ wk, const float* __restrict__ wv,
    short* __restrict__ qb, short* __restrict__ kb, short* __restrict__ vb,
    short* __restrict__ Wqb, short* __restrict__ Wkb, short* __restrict__ Wvb,
    float* __restrict__ ZF, float* __restrict__ Tv, int* __restrict__ done)
{
  const int y = blockIdx.y;
  const float* s; short* d; int i;
  if (blockIdx.x < 2048) {
    s = (y == 0) ? q : (y == 1) ? k : v;
    d = (y == 0) ? qb : (y == 1) ? kb : vb;
    i = (blockIdx.x * 256 + threadIdx.x) * 8;
    if (y == 0) {
      const int gid = blockIdx.x * 256 + threadIdx.x;
      if (gid < 8192) ZF[gid] = 0.0f;
      if (gid < 2048) Tv[gid] = 0.0f;
      if (gid < 16)   done[gid] = 0;
    }
  } else {
    s = (y == 0) ? wq : (y == 1) ? wk : wv;
    d = (y == 0) ? Wqb : (y == 1) ? Wkb : Wvb;
    i = ((int)(blockIdx.x - 2048) * 256 + threadIdx.x) * 8;
  }
  const float4 f0 = *(const float4*)(s + i);
  const float4 f1 = *(const float4*)(s + i + 4);
  s8v o;
  o[0] = f2bf_s(f0.x); o[1] = f2bf_s(f0.y); o[2] = f2bf_s(f0.z); o[3] = f2bf_s(f0.w);
  o[4] = f2bf_s(f1.x); o[5] = f2bf_s(f1.y); o[6] = f2bf_s(f1.z); o[7] = f2bf_s(f1.w);
  *(s8v*)(d + i) = o;
}

extern "C" void kernel_launch(void* const* d_in, const int* in_sizes, int n_in,
                              void* d_out, int out_size, void* d_ws, size_t ws_size,
                              hipStream_t stream) {
  const float* q   = (const float*)d_in[0];
  const float* k   = (const float*)d_in[1];
  const float* v   = (const float*)d_in[2];
  const float* WQw = (const float*)d_in[3];
  const float* WQb = (const float*)d_in[4];
  const float* WKw = (const float*)d_in[5];
  const float* WKb = (const float*)d_in[6];
  const float* WVw = (const float*)d_in[7];
  const float* WVb = (const float*)d_in[8];

  char* ws = (char*)d_ws;
  // F occupies ws[0,32M). qb/kb/Wqb/Wkb alias F (dead before any F write).
  // vb/Wvb must SURVIVE into scores_projv (concurrent with F writes) -> they
  // live in d_out scratch (out fully rewritten by the final outF phase).
  short* F   = (short*)(ws);                 // 32 MB  [4][2048][2048] (lower tiles only)
  short* qb  = (short*)(ws);                 //  8 MB  (alias F, dead after proj_qk)
  short* kb  = qb + 4194304;                 //  8 MB  (alias F)
  short* Wqb = (short*)(ws + 25165824);      //  512 KB (alias F, dead after proj_qk)
  short* Wkb = Wqb + 262144;                 //  512 KB (alias F)
  short* qp  = (short*)(ws + 33554432);      //  8 MB  [4][2048][512]
  short* kp  = (short*)(ws + 41943040);      //  8 MB
  short* vpT = (short*)(ws + 50331648);      //  8 MB  [4][512][2048]
  float* ZF  = (float*)(ws + 58720256);      // 32 KB  [4][2048]
  float* Tv  = (float*)(ws + 58753024);      //  8 KB  [4][512]
  int*   done = (int*)(ws + 58761216);       // 64 B   producer counter
  short* vb  = (short*)d_out;                //  8 MB  (out scratch [0,8M))
  short* Wvb = (short*)d_out + 4194304;      //  512 KB (out scratch [8M,8.5M))

  const dim3 blk(256);

  cvt_all<<<dim3(2176, 3), blk, 0, stream>>>(
      q, k, v, WQw, WKw, WVw, qb, kb, vb, Wqb, Wkb, Wvb, ZF, Tv, done);

  // q,k projections: 512 full tiles = exactly one round @2/CU
  proj_qk<<<dim3(512), blk, 0, stream>>>(qb, kb, Wqb, Wkb, qp, kp, WQb, WKb);

  // scores (544) + vpT projection with fused scale/Tv (256): 2 rounds
  scores_projv<<<dim3(800), blk, 0, stream>>>(
      qp, kp, F, ZF, vb, Wvb, vpT, WVb, Tv, done);

  // out = F @ vpT'^T + Tv: 64x128 tiles, K truncated at m0+64, XCD-local
  gemm_outF<<<dim3(512), blk, 0, stream>>>(F, vpT, Tv, (float*)d_out);
}